// Round 1
// baseline (905.571 us; speedup 1.0000x reference)
//
#include <hip/hip_runtime.h>
#include <hip/hip_bf16.h>
#include <cstdint>
#include <cstddef>

#define B_ 16
#define TX_ 256
#define TY_ 2048
#define C_ 80
#define H_ 256
#define NEG_ -1e9f

// ---------------------------------------------------------------------------
// Kernel 1: logp[b,x,t] = -0.5*( S1 - 2*S2 + T3[x] )/C - 0.5*mean_c(ls[x])
//   S1 = sum_c y[t,c]^2 * w[x,c],  S2 = sum_c y[t,c]*mu[x,c]*w[x,c],
//   w = exp(-2*ls).  Accumulated jointly: acc += y2*w + y*(-2*mu*w).
// grid (8 t-tiles, 16 x-tiles, 16 b), block 256 (one thread per t in tile)
// ---------------------------------------------------------------------------
__global__ __launch_bounds__(256) void logp_kernel(
    const float* __restrict__ mu, const float* __restrict__ ls,
    const float* __restrict__ y, float* __restrict__ logp_out)
{
    __shared__ float2 coef[16 * 80];   // [x][c] -> (w, -2*mu*w)
    __shared__ float  Kx[16];
    __shared__ float  yt[16 * 257];    // transposed y chunk [c_local][t], pad 257

    const int tid = threadIdx.x;
    const int t0 = blockIdx.x * 256;
    const int x0 = blockIdx.y * 16;
    const int b  = blockIdx.z;

    // pass 1: per-(x,c) coefficients
    for (int i = tid; i < 16 * 80; i += 256) {
        int c = i >> 4, x = i & 15;
        float m = mu[(size_t)(b * C_ + c) * TX_ + x0 + x];
        float l = ls[(size_t)(b * C_ + c) * TX_ + x0 + x];
        float w = expf(-2.f * l);
        coef[x * 80 + c] = make_float2(w, -2.f * m * w);
    }
    // pass 2: per-x constants (16 threads; small)
    if (tid < 16) {
        float t3 = 0.f, sls = 0.f;
        for (int c = 0; c < C_; ++c) {
            float m = mu[(size_t)(b * C_ + c) * TX_ + x0 + tid];
            float l = ls[(size_t)(b * C_ + c) * TX_ + x0 + tid];
            float w = expf(-2.f * l);
            t3 += m * m * w;
            sls += l;
        }
        Kx[tid] = -0.5f * (t3 / (float)C_) - 0.5f * (sls / (float)C_);
    }

    float acc[16];
#pragma unroll
    for (int x = 0; x < 16; ++x) acc[x] = 0.f;

    const float4* y4 = (const float4*)y;
    for (int c0 = 0; c0 < C_; c0 += 16) {
        __syncthreads();   // (first iter also covers coef/Kx writes)
        // stage y[t0..t0+255][c0..c0+15] transposed into LDS, coalesced f4 loads
        for (int f = tid; f < 1024; f += 256) {
            int t = f >> 2, k = f & 3;
            float4 v = y4[(size_t)(b * TY_ + t0 + t) * 20 + (c0 >> 2) + k];
            yt[(4 * k + 0) * 257 + t] = v.x;
            yt[(4 * k + 1) * 257 + t] = v.y;
            yt[(4 * k + 2) * 257 + t] = v.z;
            yt[(4 * k + 3) * 257 + t] = v.w;
        }
        __syncthreads();
        for (int cl = 0; cl < 16; ++cl) {
            float yv = yt[cl * 257 + tid];
            float y2 = yv * yv;
#pragma unroll
            for (int x = 0; x < 16; ++x) {
                float2 f2 = coef[x * 80 + c0 + cl];   // broadcast b64 read
                acc[x] = fmaf(y2, f2.x, fmaf(yv, f2.y, acc[x]));
            }
        }
    }
#pragma unroll
    for (int x = 0; x < 16; ++x) {
        float val = fmaf(acc[x], -0.5f / (float)C_, Kx[x]);
        logp_out[(size_t)(b * TX_ + x0 + x) * TY_ + t0 + tid] = val;
    }
}

// ---------------------------------------------------------------------------
// Kernel 2: monotonic alignment search (forward DP + backtrace), 1 wave/batch.
// Lane t owns rows 4t..4t+3.  diag bits: per column j, lane word bit
// position = 4*(j&7) + (i&3); word index = i>>2; chunk = j>>3.
// LDS diag = 256 chunks * 64 lanes * 4B = 64 KiB.
// ---------------------------------------------------------------------------
__global__ __launch_bounds__(64) void mas_kernel(
    const float* __restrict__ logp, const int* __restrict__ xlen,
    const int* __restrict__ ylen, float* __restrict__ dr_out,
    int* __restrict__ idx_out)
{
    __shared__ unsigned int diag[256 * 64];   // 64 KiB
    const int lane = threadIdx.x;
    const int b = blockIdx.x;
    const int x_len = xlen[b];
    const int y_len = ylen[b];

    float* drb = dr_out + (size_t)b * TX_;
    for (int i = lane; i < TX_; i += 64) drb[i] = 0.f;   // zero durations

    const float* lp = logp + ((size_t)b * TX_ + lane * 4) * TY_;

    float v0 = (lane == 0) ? 0.f : NEG_, v1 = NEG_, v2 = NEG_, v3 = NEG_;
    const bool isl0 = (lane == 0);

    float c0 = lp[0], c1 = lp[TY_], c2 = lp[2 * TY_], c3 = lp[3 * TY_];
    unsigned int accb = 0;
    for (int j = 0; j < y_len; ++j) {
        int jn = (j + 1 < y_len) ? j + 1 : j;          // clamp (no OOB at end)
        float n0 = lp[jn], n1 = lp[TY_ + jn], n2 = lp[2 * TY_ + jn], n3 = lp[3 * TY_ + jn];
        float sf = __shfl_up(v3, 1);
        float sh0 = isl0 ? NEG_ : sf;
        // diag bits from state BEFORE this column's update (matches reference)
        unsigned nib = (unsigned)(sh0 > v0)
                     | ((unsigned)(v0 > v1) << 1)
                     | ((unsigned)(v1 > v2) << 2)
                     | ((unsigned)(v2 > v3) << 3);
        accb |= nib << ((j & 7) << 2);
        float m0 = fmaxf(v0, sh0);
        float m1 = fmaxf(v1, v0);
        float m2 = fmaxf(v2, v1);
        float m3 = fmaxf(v3, v2);
        v0 = m0 + c0; v1 = m1 + c1; v2 = m2 + c2; v3 = m3 + c3;
        c0 = n0; c1 = n1; c2 = n2; c3 = n3;
        if ((j & 7) == 7) { diag[(j >> 3) * 64 + lane] = accb; accb = 0; }
    }
    if (y_len & 7) diag[((y_len - 1) >> 3) * 64 + lane] = accb;
    __syncthreads();

    // -------- backtrace: lane 0, register-windowed (5 words/chunk, prefetch) --
    if (lane == 0) {
        int i = x_len - 1;
        int cnt = 0;
        int jc = (y_len - 1) >> 3;
        int wb = i >> 2;
        unsigned W0, W1, W2, W3, W4;
        unsigned P0 = 0, P1 = 0, P2 = 0, P3 = 0, P4 = 0;
        int pb;
        {
            const unsigned* dg = &diag[jc * 64];
            W0 = dg[wb];
            W1 = dg[wb >= 1 ? wb - 1 : 0];
            W2 = dg[wb >= 2 ? wb - 2 : 0];
            W3 = dg[wb >= 3 ? wb - 3 : 0];
            W4 = dg[wb >= 4 ? wb - 4 : 0];
        }
        pb = wb;
        if (jc > 0) {
            const unsigned* dg = &diag[(jc - 1) * 64];
            P0 = dg[pb];
            P1 = dg[pb >= 1 ? pb - 1 : 0];
            P2 = dg[pb >= 2 ? pb - 2 : 0];
            P3 = dg[pb >= 3 ? pb - 3 : 0];
            P4 = dg[pb >= 4 ? pb - 4 : 0];
        }
        int j = y_len - 1;
        int* ib = idx_out + (size_t)b * TY_;
        while (true) {
            int jlo = jc << 3;
            for (; j >= jlo; --j) {
                ib[j] = i;          // emit path row for column j
                cnt++;
                int sel = wb - (i >> 2);   // 0..4 by construction
                unsigned w = (sel == 0) ? W0 : (sel == 1) ? W1 : (sel == 2) ? W2
                           : (sel == 3) ? W3 : W4;
                unsigned bit = (w >> (((j & 7) << 2) + (i & 3))) & 1u;
                if (bit && i > 0) { drb[i] = (float)cnt; cnt = 0; --i; }
            }
            if (jc == 0) break;
            --jc;
            W0 = P0; W1 = P1; W2 = P2; W3 = P3; W4 = P4; wb = pb;
            if (jc > 0) {
                pb = i >> 2;
                const unsigned* dg = &diag[(jc - 1) * 64];
                P0 = dg[pb];
                P1 = dg[pb >= 1 ? pb - 1 : 0];
                P2 = dg[pb >= 2 ? pb - 2 : 0];
                P3 = dg[pb >= 3 ? pb - 3 : 0];
                P4 = dg[pb >= 4 ? pb - 4 : 0];
            }
        }
        drb[i] = (float)cnt;   // final run
    }
}

// ---------------------------------------------------------------------------
// Kernel 3: emit attn (one-hot path) and o_en_ex (gather of en rows).
// grid (16 b, 512): blockIdx.y<256 -> attn row x; else -> o_en row h.
// ---------------------------------------------------------------------------
__global__ __launch_bounds__(256) void emit_kernel(
    const float* __restrict__ en, const int* __restrict__ ylen,
    const int* __restrict__ idx_in, float* __restrict__ o_en,
    float* __restrict__ attn)
{
    const int tid = threadIdx.x;
    const int b = blockIdx.x;
    const int r = blockIdx.y;
    const int y_len = ylen[b];
    const int* ib = idx_in + (size_t)b * TY_;

    if (r < 256) {
        const int x = r;
        float* out = attn + ((size_t)b * TX_ + x) * TY_;
        for (int t = tid; t < TY_; t += 256) {
            int ii = ib[t];
            out[t] = (t < y_len && ii == x) ? 1.f : 0.f;
        }
    } else {
        const int h = r - 256;
        __shared__ float enr[256];
        enr[tid] = en[((size_t)b * H_ + h) * TX_ + tid];
        __syncthreads();
        float* out = o_en + ((size_t)b * H_ + h) * TY_;
        for (int t = tid; t < TY_; t += 256) {
            int ii = ib[t];
            bool a = (t < y_len);
            int is = a ? ii : 0;        // guard: idx undefined for t>=y_len
            out[t] = a ? enr[is] : 0.f;
        }
    }
}

// ---------------------------------------------------------------------------
extern "C" void kernel_launch(void* const* d_in, const int* in_sizes, int n_in,
                              void* d_out, int out_size, void* d_ws, size_t ws_size,
                              hipStream_t stream)
{
    const float* en = (const float*)d_in[0];
    const float* mu = (const float*)d_in[1];
    const float* ls = (const float*)d_in[2];
    const float* y  = (const float*)d_in[3];
    const int* xl   = (const int*)d_in[4];
    const int* yl   = (const int*)d_in[5];

    float* o_en = (float*)d_out;                       // [16,256,2048]
    float* attn = o_en + (size_t)B_ * TX_ * TY_;       // [16,256,2048]
    float* dr   = attn + (size_t)B_ * TX_ * TY_;       // [16,256]
    float* logp = dr + (size_t)B_ * TX_;               // [16,256,2048]

    int* idxArr = (int*)d_ws;                          // [16,2048] path rows

    dim3 g1(8, 16, 16);
    logp_kernel<<<g1, 256, 0, stream>>>(mu, ls, y, logp);

    mas_kernel<<<dim3(16), dim3(64), 0, stream>>>(logp, xl, yl, dr, idxArr);

    dim3 g3(16, 512);
    emit_kernel<<<g3, 256, 0, stream>>>(en, yl, idxArr, o_en, attn);
}

// Round 2
// 576.608 us; speedup vs baseline: 1.5705x; 1.5705x over previous
//
#include <hip/hip_runtime.h>
#include <hip/hip_bf16.h>
#include <cstdint>
#include <cstddef>

#define B_ 16
#define TX_ 256
#define TY_ 2048
#define C_ 80
#define H_ 256
#define NEG_ -1e9f

// ---------------------------------------------------------------------------
// Kernel 1: logp[b,x,t] = -0.5*( S1 - 2*S2 + T3[x] )/C - 0.5*mean_c(ls[x])
// Register tile: 16 x * 4 t per thread (VALU-bound: 128 FMA per 17 LDS ops).
// Also emits transposed logp_t [B][TY][TX] (into the attn slot of d_out) so
// the MAS kernel can read DP columns with coalesced float4 loads.
// grid (2 t-tiles of 1024, 16 x-tiles of 16, 16 b), block 256.
// ---------------------------------------------------------------------------
__global__ __launch_bounds__(256) void logp_kernel(
    const float* __restrict__ mu, const float* __restrict__ ls,
    const float* __restrict__ y, float* __restrict__ logp_out,
    float* __restrict__ logp_t)
{
    __shared__ float2 coef[16 * 80];      // [x][c] -> (w, -2*mu*w)     10240 B
    __shared__ float  aux[16 * 80];       // [x][c] -> mu^2*w + ls       5120 B
    __shared__ float  Kx[16];             //                               64 B
    __shared__ float  yt[16 * 1028];      // [c_local][t], pad 1028     65792 B
                                          // total 81216 B <= 80 KiB -> 2 blk/CU

    const int tid = threadIdx.x;
    const int t0 = blockIdx.x * 1024;
    const int x0 = blockIdx.y * 16;
    const int b  = blockIdx.z;

    // pass 1: per-(x,c) coefficients + Kx partials
    for (int i = tid; i < 16 * 80; i += 256) {
        int c = i >> 4, x = i & 15;
        float m = mu[(size_t)(b * C_ + c) * TX_ + x0 + x];
        float l = ls[(size_t)(b * C_ + c) * TX_ + x0 + x];
        float w = __expf(-2.f * l);
        coef[x * 80 + c] = make_float2(w, -2.f * m * w);
        aux[x * 80 + c]  = fmaf(m * m, w, l);
    }
    __syncthreads();
    if (tid < 16) {
        float s = 0.f;
        for (int c = 0; c < C_; ++c) s += aux[tid * 80 + c];
        Kx[tid] = -0.5f * s / (float)C_;
    }

    float acc[16][4];
#pragma unroll
    for (int x = 0; x < 16; ++x)
#pragma unroll
        for (int r = 0; r < 4; ++r) acc[x][r] = 0.f;

    const float4* y4 = (const float4*)y;
    for (int c0 = 0; c0 < C_; c0 += 16) {
        __syncthreads();
        // stage y[t0..t0+1023][c0..c0+15] transposed, coalesced f4 loads
        for (int it = 0; it < 16; ++it) {
            int f = tid + it * 256;       // f over (t,k): 1024 t * 4 f4
            int t = f >> 2, k = f & 3;
            float4 v = y4[(size_t)(b * TY_ + t0 + t) * 20 + (c0 >> 2) + k];
            yt[(4 * k + 0) * 1028 + t] = v.x;
            yt[(4 * k + 1) * 1028 + t] = v.y;
            yt[(4 * k + 2) * 1028 + t] = v.z;
            yt[(4 * k + 3) * 1028 + t] = v.w;
        }
        __syncthreads();
        for (int cl = 0; cl < 16; ++cl) {
            const float4 yv = *reinterpret_cast<const float4*>(&yt[cl * 1028 + 4 * tid]);
            float4 y2 = make_float4(yv.x * yv.x, yv.y * yv.y, yv.z * yv.z, yv.w * yv.w);
#pragma unroll
            for (int x = 0; x < 16; ++x) {
                float2 f2 = coef[x * 80 + c0 + cl];   // broadcast b64 read
                acc[x][0] = fmaf(y2.x, f2.x, fmaf(yv.x, f2.y, acc[x][0]));
                acc[x][1] = fmaf(y2.y, f2.x, fmaf(yv.y, f2.y, acc[x][1]));
                acc[x][2] = fmaf(y2.z, f2.x, fmaf(yv.z, f2.y, acc[x][2]));
                acc[x][3] = fmaf(y2.w, f2.x, fmaf(yv.w, f2.y, acc[x][3]));
            }
        }
    }

    // epilogue: finalize, write logp [b,x,t] and logp_t [b,t,x]
#pragma unroll
    for (int x = 0; x < 16; ++x) {
        float kx = Kx[x];
#pragma unroll
        for (int r = 0; r < 4; ++r) acc[x][r] = fmaf(acc[x][r], -0.5f / (float)C_, kx);
        float4 out = make_float4(acc[x][0], acc[x][1], acc[x][2], acc[x][3]);
        *reinterpret_cast<float4*>(
            &logp_out[(size_t)(b * TX_ + x0 + x) * TY_ + t0 + 4 * tid]) = out;
    }
#pragma unroll
    for (int r = 0; r < 4; ++r) {
#pragma unroll
        for (int q = 0; q < 4; ++q) {
            float4 out = make_float4(acc[4 * q + 0][r], acc[4 * q + 1][r],
                                     acc[4 * q + 2][r], acc[4 * q + 3][r]);
            *reinterpret_cast<float4*>(
                &logp_t[(size_t)(b * TY_ + t0 + 4 * tid + r) * TX_ + x0 + 4 * q]) = out;
        }
    }
}

// ---------------------------------------------------------------------------
// Kernel 2: monotonic alignment search (forward DP + backtrace), 1 wave/batch.
// Reads transposed logp_t: one DP column = 256 contiguous floats = one
// coalesced float4/lane wave load. 32-deep register prefetch ring hides
// ~900-cycle memory latency behind ~30 cy/column of DP work.
// Lane owns rows 4l..4l+3; cross-lane carry via one __shfl_up per column.
// diag bits packed 4/column/lane -> 64 KiB LDS.
// ---------------------------------------------------------------------------
__global__ __launch_bounds__(64) void mas_kernel(
    const float* __restrict__ logp_t, const int* __restrict__ xlen,
    const int* __restrict__ ylen, float* __restrict__ dr_out,
    int* __restrict__ idx_out)
{
    __shared__ unsigned int diag[256 * 64];   // 64 KiB
    const int lane = threadIdx.x;
    const int b = blockIdx.x;
    const int x_len = xlen[b];
    const int y_len = ylen[b];

    float* drb = dr_out + (size_t)b * TX_;
    for (int i = lane; i < TX_; i += 64) drb[i] = 0.f;

    const float4* col = (const float4*)(logp_t + (size_t)b * TY_ * TX_);

    float4 buf[32];
#pragma unroll
    for (int k = 0; k < 32; ++k) buf[k] = col[(size_t)k * 64 + lane];

    float v0 = (lane == 0) ? 0.f : NEG_, v1 = NEG_, v2 = NEG_, v3 = NEG_;
    const bool isl0 = (lane == 0);
    unsigned int accb = 0;

    for (int j0 = 0; j0 < TY_; j0 += 32) {
#pragma unroll
        for (int k = 0; k < 32; ++k) {
            const int j = j0 + k;
            float4 c = buf[k];
            int jn = j + 32; jn = (jn < TY_) ? jn : (TY_ - 1);
            buf[k] = col[(size_t)jn * 64 + lane];      // prefetch 32 ahead
            float sf = __shfl_up(v3, 1);
            float sh0 = isl0 ? NEG_ : sf;
            // diag bits from state BEFORE this column's update (ref semantics)
            unsigned nib = (unsigned)(sh0 > v0)
                         | ((unsigned)(v0 > v1) << 1)
                         | ((unsigned)(v1 > v2) << 2)
                         | ((unsigned)(v2 > v3) << 3);
            accb |= nib << ((j & 7) << 2);
            float m0 = fmaxf(v0, sh0);
            float m1 = fmaxf(v1, v0);
            float m2 = fmaxf(v2, v1);
            float m3 = fmaxf(v3, v2);
            v0 = m0 + c.x; v1 = m1 + c.y; v2 = m2 + c.z; v3 = m3 + c.w;
            if ((j & 7) == 7) { diag[(j >> 3) * 64 + lane] = accb; accb = 0; }
        }
    }
    __syncthreads();

    // -------- backtrace: lane 0, register-windowed (5 words/chunk, prefetch) --
    if (lane == 0) {
        int i = x_len - 1;
        int cnt = 0;
        int jc = (y_len - 1) >> 3;
        int wb = i >> 2;
        unsigned W0, W1, W2, W3, W4;
        unsigned P0 = 0, P1 = 0, P2 = 0, P3 = 0, P4 = 0;
        int pb;
        {
            const unsigned* dg = &diag[jc * 64];
            W0 = dg[wb];
            W1 = dg[wb >= 1 ? wb - 1 : 0];
            W2 = dg[wb >= 2 ? wb - 2 : 0];
            W3 = dg[wb >= 3 ? wb - 3 : 0];
            W4 = dg[wb >= 4 ? wb - 4 : 0];
        }
        pb = wb;
        if (jc > 0) {
            const unsigned* dg = &diag[(jc - 1) * 64];
            P0 = dg[pb];
            P1 = dg[pb >= 1 ? pb - 1 : 0];
            P2 = dg[pb >= 2 ? pb - 2 : 0];
            P3 = dg[pb >= 3 ? pb - 3 : 0];
            P4 = dg[pb >= 4 ? pb - 4 : 0];
        }
        int j = y_len - 1;
        int* ib = idx_out + (size_t)b * TY_;
        while (true) {
            int jlo = jc << 3;
            for (; j >= jlo; --j) {
                ib[j] = i;
                cnt++;
                int sel = wb - (i >> 2);   // 0..4 by construction
                unsigned w = (sel == 0) ? W0 : (sel == 1) ? W1 : (sel == 2) ? W2
                           : (sel == 3) ? W3 : W4;
                unsigned bit = (w >> (((j & 7) << 2) + (i & 3))) & 1u;
                if (bit && i > 0) { drb[i] = (float)cnt; cnt = 0; --i; }
            }
            if (jc == 0) break;
            --jc;
            W0 = P0; W1 = P1; W2 = P2; W3 = P3; W4 = P4; wb = pb;
            if (jc > 0) {
                pb = i >> 2;
                const unsigned* dg = &diag[(jc - 1) * 64];
                P0 = dg[pb];
                P1 = dg[pb >= 1 ? pb - 1 : 0];
                P2 = dg[pb >= 2 ? pb - 2 : 0];
                P3 = dg[pb >= 3 ? pb - 3 : 0];
                P4 = dg[pb >= 4 ? pb - 4 : 0];
            }
        }
        drb[i] = (float)cnt;
    }
}

// ---------------------------------------------------------------------------
// Kernel 3: emit attn (one-hot path) and o_en_ex (gather of en rows).
// grid (16 b, 512): blockIdx.y<256 -> attn row x; else -> o_en row h.
// ---------------------------------------------------------------------------
__global__ __launch_bounds__(256) void emit_kernel(
    const float* __restrict__ en, const int* __restrict__ ylen,
    const int* __restrict__ idx_in, float* __restrict__ o_en,
    float* __restrict__ attn)
{
    const int tid = threadIdx.x;
    const int b = blockIdx.x;
    const int r = blockIdx.y;
    const int y_len = ylen[b];
    const int* ib = idx_in + (size_t)b * TY_;

    if (r < 256) {
        const int x = r;
        float* out = attn + ((size_t)b * TX_ + x) * TY_;
        for (int t = tid; t < TY_; t += 256) {
            int ii = ib[t];
            out[t] = (t < y_len && ii == x) ? 1.f : 0.f;
        }
    } else {
        const int h = r - 256;
        __shared__ float enr[256];
        enr[tid] = en[((size_t)b * H_ + h) * TX_ + tid];
        __syncthreads();
        float* out = o_en + ((size_t)b * H_ + h) * TY_;
        for (int t = tid; t < TY_; t += 256) {
            int ii = ib[t];
            bool a = (t < y_len);
            int is = a ? ii : 0;
            out[t] = a ? enr[is] : 0.f;
        }
    }
}

// ---------------------------------------------------------------------------
extern "C" void kernel_launch(void* const* d_in, const int* in_sizes, int n_in,
                              void* d_out, int out_size, void* d_ws, size_t ws_size,
                              hipStream_t stream)
{
    const float* en = (const float*)d_in[0];
    const float* mu = (const float*)d_in[1];
    const float* ls = (const float*)d_in[2];
    const float* y  = (const float*)d_in[3];
    const int* xl   = (const int*)d_in[4];
    const int* yl   = (const int*)d_in[5];

    float* o_en = (float*)d_out;                       // [16,256,2048]
    float* attn = o_en + (size_t)B_ * TX_ * TY_;       // [16,256,2048]
    float* dr   = attn + (size_t)B_ * TX_ * TY_;       // [16,256]
    float* logp = dr + (size_t)B_ * TX_;               // [16,256,2048]

    // transposed logp lives temporarily in the attn slot (overwritten by emit)
    float* logp_t = attn;
    int* idxArr = (int*)d_ws;                          // [16,2048] path rows

    dim3 g1(2, 16, 16);
    logp_kernel<<<g1, 256, 0, stream>>>(mu, ls, y, logp, logp_t);

    mas_kernel<<<dim3(16), dim3(64), 0, stream>>>(logp_t, xl, yl, dr, idxArr);

    dim3 g3(16, 512);
    emit_kernel<<<g3, 256, 0, stream>>>(en, yl, idxArr, o_en, attn);
}

// Round 3
// 451.845 us; speedup vs baseline: 2.0042x; 1.2761x over previous
//
#include <hip/hip_runtime.h>
#include <hip/hip_bf16.h>
#include <cstdint>
#include <cstddef>

#define B_ 16
#define TX_ 256
#define TY_ 2048
#define C_ 80
#define H_ 256
#define NEG_ -1e9f
#define NEG_I (int)0xCE6E6B28   // bit pattern of -1e9f

// ---------------------------------------------------------------------------
// Kernel 1: logp[b,x,t] = -0.5*( S1 - 2*S2 + T3[x] )/C - 0.5*mean_c(ls[x])
// Register tile: 16 x * 4 t per thread. Also emits transposed logp_t [B,Ty,Tx]
// (into the attn slot of d_out) so MAS reads DP columns coalesced.
// ---------------------------------------------------------------------------
__global__ __launch_bounds__(256) void logp_kernel(
    const float* __restrict__ mu, const float* __restrict__ ls,
    const float* __restrict__ y, float* __restrict__ logp_out,
    float* __restrict__ logp_t)
{
    __shared__ float2 coef[16 * 80];
    __shared__ float  aux[16 * 80];
    __shared__ float  Kx[16];
    __shared__ float  yt[16 * 1028];

    const int tid = threadIdx.x;
    const int t0 = blockIdx.x * 1024;
    const int x0 = blockIdx.y * 16;
    const int b  = blockIdx.z;

    for (int i = tid; i < 16 * 80; i += 256) {
        int c = i >> 4, x = i & 15;
        float m = mu[(size_t)(b * C_ + c) * TX_ + x0 + x];
        float l = ls[(size_t)(b * C_ + c) * TX_ + x0 + x];
        float w = __expf(-2.f * l);
        coef[x * 80 + c] = make_float2(w, -2.f * m * w);
        aux[x * 80 + c]  = fmaf(m * m, w, l);
    }
    __syncthreads();
    if (tid < 16) {
        float s = 0.f;
        for (int c = 0; c < C_; ++c) s += aux[tid * 80 + c];
        Kx[tid] = -0.5f * s / (float)C_;
    }

    float acc[16][4];
#pragma unroll
    for (int x = 0; x < 16; ++x)
#pragma unroll
        for (int r = 0; r < 4; ++r) acc[x][r] = 0.f;

    const float4* y4 = (const float4*)y;
    for (int c0 = 0; c0 < C_; c0 += 16) {
        __syncthreads();
        for (int it = 0; it < 16; ++it) {
            int f = tid + it * 256;
            int t = f >> 2, k = f & 3;
            float4 v = y4[(size_t)(b * TY_ + t0 + t) * 20 + (c0 >> 2) + k];
            yt[(4 * k + 0) * 1028 + t] = v.x;
            yt[(4 * k + 1) * 1028 + t] = v.y;
            yt[(4 * k + 2) * 1028 + t] = v.z;
            yt[(4 * k + 3) * 1028 + t] = v.w;
        }
        __syncthreads();
        for (int cl = 0; cl < 16; ++cl) {
            const float4 yv = *reinterpret_cast<const float4*>(&yt[cl * 1028 + 4 * tid]);
            float4 y2 = make_float4(yv.x * yv.x, yv.y * yv.y, yv.z * yv.z, yv.w * yv.w);
#pragma unroll
            for (int x = 0; x < 16; ++x) {
                float2 f2 = coef[x * 80 + c0 + cl];
                acc[x][0] = fmaf(y2.x, f2.x, fmaf(yv.x, f2.y, acc[x][0]));
                acc[x][1] = fmaf(y2.y, f2.x, fmaf(yv.y, f2.y, acc[x][1]));
                acc[x][2] = fmaf(y2.z, f2.x, fmaf(yv.z, f2.y, acc[x][2]));
                acc[x][3] = fmaf(y2.w, f2.x, fmaf(yv.w, f2.y, acc[x][3]));
            }
        }
    }

#pragma unroll
    for (int x = 0; x < 16; ++x) {
        float kx = Kx[x];
#pragma unroll
        for (int r = 0; r < 4; ++r) acc[x][r] = fmaf(acc[x][r], -0.5f / (float)C_, kx);
        float4 out = make_float4(acc[x][0], acc[x][1], acc[x][2], acc[x][3]);
        *reinterpret_cast<float4*>(
            &logp_out[(size_t)(b * TX_ + x0 + x) * TY_ + t0 + 4 * tid]) = out;
    }
#pragma unroll
    for (int r = 0; r < 4; ++r) {
#pragma unroll
        for (int q = 0; q < 4; ++q) {
            float4 out = make_float4(acc[4 * q + 0][r], acc[4 * q + 1][r],
                                     acc[4 * q + 2][r], acc[4 * q + 3][r]);
            *reinterpret_cast<float4*>(
                &logp_t[(size_t)(b * TY_ + t0 + 4 * tid + r) * TX_ + x0 + 4 * q]) = out;
        }
    }
}

// ---------------------------------------------------------------------------
// Kernel 2: MAS. Forward: 1 wave/b, lane owns rows 4l..4l+3, 16-deep float4
// prefetch ring (64 VGPR — no spill), DPP wave_shr1 for the cross-lane carry
// (2-cy VALU instead of ds_bpermute). Decision nibbles packed 8 cols/dword.
// Backtrace: lane 0, 64-bit row-window (8 rows) with chunk-ahead prefetch;
// <=1 window crossing per 8-col chunk by construction.
// ---------------------------------------------------------------------------
__global__ __launch_bounds__(64) void mas_kernel(
    const float* __restrict__ logp_t, const int* __restrict__ xlen,
    const int* __restrict__ ylen, float* __restrict__ dr_out,
    int* __restrict__ idx_out)
{
    __shared__ unsigned int diag[256 * 64];   // 64 KiB: [chunk][rowword]
    const int lane = threadIdx.x;
    const int b = blockIdx.x;
    const int x_len = xlen[b];
    const int y_len = ylen[b];

    float* drb = dr_out + (size_t)b * TX_;
    for (int i = lane; i < TX_; i += 64) drb[i] = 0.f;

    const float4* col = (const float4*)(logp_t + (size_t)b * TY_ * TX_);

    float4 buf[16];
#pragma unroll
    for (int k = 0; k < 16; ++k) buf[k] = col[(size_t)k * 64 + lane];

    float v0 = (lane == 0) ? 0.f : NEG_, v1 = NEG_, v2 = NEG_, v3 = NEG_;
    unsigned int accb = 0;

    const int jmax = (y_len + 15) & ~15;
    for (int j0 = 0; j0 < jmax; j0 += 16) {
#pragma unroll
        for (int k = 0; k < 16; ++k) {
            const int j = j0 + k;
            float4 c = buf[k];
            int jn = j + 16; jn = (jn < TY_) ? jn : (TY_ - 1);
            buf[k] = col[(size_t)jn * 64 + lane];
            // carry: lane l gets v3 of lane l-1; lane 0 gets NEG (old value)
            int shi = __builtin_amdgcn_update_dpp(
                NEG_I, __float_as_int(v3), 0x138 /*wave_shr1*/, 0xF, 0xF, false);
            float sh0 = __int_as_float(shi);
            // decision bits from state BEFORE the update (ref semantics);
            // (k&7) is a compile-time constant -> literal masks
            accb |= (sh0 > v0) ? (1u << ((k & 7) * 4)) : 0u;
            accb |= (v0 > v1) ? (2u << ((k & 7) * 4)) : 0u;
            accb |= (v1 > v2) ? (4u << ((k & 7) * 4)) : 0u;
            accb |= (v2 > v3) ? (8u << ((k & 7) * 4)) : 0u;
            float m0 = fmaxf(v0, sh0);
            float m1 = fmaxf(v1, v0);
            float m2 = fmaxf(v2, v1);
            float m3 = fmaxf(v3, v2);
            v0 = m0 + c.x; v1 = m1 + c.y; v2 = m2 + c.z; v3 = m3 + c.w;
            if ((k & 7) == 7) { diag[(j >> 3) * 64 + lane] = accb; accb = 0; }
        }
    }
    __syncthreads();

    if (lane == 0) {
        int i = x_len - 1;
        int cnt = 0;
        int j = y_len - 1;
        int jc = j >> 3;
        int jb = j & 7;
        int p = i >> 3;          // 8-row pair index
        int ep = p;              // pair index at entry of current chunk

        auto pair = [&](int cc, int pp) -> unsigned long long {
            pp = pp < 0 ? 0 : pp;
            uint2 u = *(const uint2*)&diag[cc * 64 + 2 * pp];
            return (unsigned long long)u.x | ((unsigned long long)u.y << 32);
        };

        unsigned long long W  = pair(jc, p);
        unsigned long long Wl = pair(jc, p - 1);
        unsigned long long N  = (jc > 0) ? pair(jc - 1, p) : 0ULL;
        unsigned long long Nl = (jc > 0) ? pair(jc - 1, p - 1) : 0ULL;

        int* ib = idx_out + (size_t)b * TY_;
        while (true) {
            ib[j] = i;
            cnt++;
            int pos = (((i >> 2) & 1) << 5) | (jb << 2) | (i & 3);
            if (((W >> pos) & 1ULL) && i > 0) {
                drb[i] = (float)cnt; cnt = 0; --i;
                if ((i & 7) == 7) {           // crossed 8-row window
                    --p; W = Wl;
                    Wl = pair(jc, p - 1);
                }
            }
            --j; --jb;
            if (jb < 0) {
                if (jc == 0) break;
                --jc; jb = 7;
                W = (p == ep) ? N : Nl;       // p in {ep, ep-1} by construction
                ep = p;
                Wl = pair(jc, p - 1);
                N  = (jc > 0) ? pair(jc - 1, p) : 0ULL;
                Nl = (jc > 0) ? pair(jc - 1, p - 1) : 0ULL;
            }
        }
        drb[i] = (float)cnt;
    }
}

// ---------------------------------------------------------------------------
// Kernel 3: emit attn (one-hot path) and o_en_ex (gather of en rows).
// ---------------------------------------------------------------------------
__global__ __launch_bounds__(256) void emit_kernel(
    const float* __restrict__ en, const int* __restrict__ ylen,
    const int* __restrict__ idx_in, float* __restrict__ o_en,
    float* __restrict__ attn)
{
    const int tid = threadIdx.x;
    const int b = blockIdx.x;
    const int r = blockIdx.y;
    const int y_len = ylen[b];
    const int* ib = idx_in + (size_t)b * TY_;

    if (r < 256) {
        const int x = r;
        float* out = attn + ((size_t)b * TX_ + x) * TY_;
        for (int t = tid; t < TY_; t += 256) {
            int ii = ib[t];
            out[t] = (t < y_len && ii == x) ? 1.f : 0.f;
        }
    } else {
        const int h = r - 256;
        __shared__ float enr[256];
        enr[tid] = en[((size_t)b * H_ + h) * TX_ + tid];
        __syncthreads();
        float* out = o_en + ((size_t)b * H_ + h) * TY_;
        for (int t = tid; t < TY_; t += 256) {
            int ii = ib[t];
            bool a = (t < y_len);
            int is = a ? ii : 0;
            out[t] = a ? enr[is] : 0.f;
        }
    }
}

// ---------------------------------------------------------------------------
extern "C" void kernel_launch(void* const* d_in, const int* in_sizes, int n_in,
                              void* d_out, int out_size, void* d_ws, size_t ws_size,
                              hipStream_t stream)
{
    const float* en = (const float*)d_in[0];
    const float* mu = (const float*)d_in[1];
    const float* ls = (const float*)d_in[2];
    const float* y  = (const float*)d_in[3];
    const int* xl   = (const int*)d_in[4];
    const int* yl   = (const int*)d_in[5];

    float* o_en = (float*)d_out;                       // [16,256,2048]
    float* attn = o_en + (size_t)B_ * TX_ * TY_;       // [16,256,2048]
    float* dr   = attn + (size_t)B_ * TX_ * TY_;       // [16,256]
    float* logp = dr + (size_t)B_ * TX_;               // [16,256,2048]

    float* logp_t = attn;                              // scratch in attn slot
    int* idxArr = (int*)d_ws;                          // [16,2048]

    dim3 g1(2, 16, 16);
    logp_kernel<<<g1, 256, 0, stream>>>(mu, ls, y, logp, logp_t);

    mas_kernel<<<dim3(16), dim3(64), 0, stream>>>(logp_t, xl, yl, dr, idxArr);

    dim3 g3(16, 512);
    emit_kernel<<<g3, 256, 0, stream>>>(en, yl, idxArr, o_en, attn);
}